// Round 1
// baseline (623.170 us; speedup 1.0000x reference)
//
#include <hip/hip_runtime.h>
#include <hip/hip_bf16.h>
#include <float.h>

#define N_NODES 100000
#define N_EDGES 1600000
#define HIDDEN 64
#define N_GRAPHS 128
#define NEG_SLOPE 0.2f
#define ETOT (N_EDGES + N_NODES)

#define SCAN_CHUNK 512
#define SCAN_BLOCKS ((N_NODES + SCAN_CHUNK - 1) / SCAN_CHUNK)  // 196

// ---------------- CSR build ----------------

__global__ void k_init_deg(int* __restrict__ deg) {
    int i = blockIdx.x * blockDim.x + threadIdx.x;
    if (i < N_NODES) deg[i] = 1;  // self loop
}

__global__ void k_hist(const int* __restrict__ dst, int* __restrict__ deg) {
    int e = blockIdx.x * blockDim.x + threadIdx.x;
    if (e < N_EDGES) atomicAdd(&deg[dst[e]], 1);
}

__global__ void k_scan1(const int* __restrict__ deg, int* __restrict__ tmp,
                        int* __restrict__ bsum) {
    __shared__ int s[SCAN_CHUNK];
    int t = threadIdx.x;
    int gi = blockIdx.x * SCAN_CHUNK + t;
    int v = (gi < N_NODES) ? deg[gi] : 0;
    s[t] = v;
    __syncthreads();
    for (int off = 1; off < SCAN_CHUNK; off <<= 1) {
        int u = (t >= off) ? s[t - off] : 0;
        __syncthreads();
        s[t] += u;
        __syncthreads();
    }
    if (gi < N_NODES) tmp[gi] = s[t];  // inclusive within block
    if (t == SCAN_CHUNK - 1) bsum[blockIdx.x] = s[t];
}

__global__ void k_scan2(const int* __restrict__ bsum, int* __restrict__ boffs) {
    __shared__ int s[256];
    int t = threadIdx.x;
    int v = (t < SCAN_BLOCKS) ? bsum[t] : 0;
    s[t] = v;
    __syncthreads();
    for (int off = 1; off < 256; off <<= 1) {
        int u = (t >= off) ? s[t - off] : 0;
        __syncthreads();
        s[t] += u;
        __syncthreads();
    }
    if (t < SCAN_BLOCKS) boffs[t] = s[t] - v;  // exclusive
}

__global__ void k_scan3(const int* __restrict__ tmp, const int* __restrict__ boffs,
                        int* __restrict__ rowptr, int* __restrict__ next) {
    int i = blockIdx.x * blockDim.x + threadIdx.x;
    if (i < N_NODES) {
        int val = tmp[i] + boffs[i >> 9];  // SCAN_CHUNK == 512
        rowptr[i + 1] = val;
        next[i + 1] = val;
        if (i == 0) { rowptr[0] = 0; next[0] = 0; }
    }
}

__global__ void k_scatter(const int* __restrict__ e0, const int* __restrict__ e1,
                          int* __restrict__ next, int* __restrict__ col) {
    int idx = blockIdx.x * blockDim.x + threadIdx.x;
    if (idx < ETOT) {
        int s, d;
        if (idx < N_EDGES) { s = e0[idx]; d = e1[idx]; }
        else { s = d = idx - N_EDGES; }
        int pos = atomicAdd(&next[d], 1);
        col[pos] = s;
    }
}

// ---------------- per-layer GEMM + attention scores ----------------
// hW = h @ W  (h from embed gather at layer 0)
// s_src[i] = dot(hW[i], a_s); s_dst[i] = dot(hW[i], a_d)

__global__ __launch_bounds__(256) void k_gemm_score(
    const float* __restrict__ h, const int* __restrict__ x,
    const float* __restrict__ embed, const float* __restrict__ W,
    const float* __restrict__ a_s, const float* __restrict__ a_d,
    float* __restrict__ hW, float* __restrict__ s_src, float* __restrict__ s_dst,
    int layer0)
{
    __shared__ float Wl[64 * 64];
    __shared__ float hT[64 * 68];  // [k][r], pitch 68 (16B-aligned rows, broken pow2 stride)
    int t = threadIdx.x;
    int r0 = blockIdx.x * 64;

    for (int i = t; i < 4096; i += 256) Wl[i] = W[i];
    for (int i = t; i < 4096; i += 256) {
        int r = i >> 6, k = i & 63;
        int row = r0 + r;
        float v = 0.f;
        if (row < N_NODES)
            v = layer0 ? embed[x[row] * 64 + k] : h[row * 64 + k];
        hT[k * 68 + r] = v;
    }
    __syncthreads();

    int tcol = t & 15;   // 4 cols starting at tcol*4
    int trow = t >> 4;   // 4 rows starting at trow*4
    float acc[4][4];
#pragma unroll
    for (int i = 0; i < 4; ++i)
#pragma unroll
        for (int j = 0; j < 4; ++j) acc[i][j] = 0.f;

    for (int k = 0; k < 64; ++k) {
        float4 va = *(const float4*)&hT[k * 68 + trow * 4];
        float4 vb = *(const float4*)&Wl[k * 64 + tcol * 4];
        float a[4] = {va.x, va.y, va.z, va.w};
        float b[4] = {vb.x, vb.y, vb.z, vb.w};
#pragma unroll
        for (int i = 0; i < 4; ++i)
#pragma unroll
            for (int j = 0; j < 4; ++j) acc[i][j] = fmaf(a[i], b[j], acc[i][j]);
    }

    float4 as4 = *(const float4*)&a_s[tcol * 4];
    float4 ad4 = *(const float4*)&a_d[tcol * 4];
    float asr[4] = {as4.x, as4.y, as4.z, as4.w};
    float adr[4] = {ad4.x, ad4.y, ad4.z, ad4.w};

#pragma unroll
    for (int i = 0; i < 4; ++i) {
        int row = r0 + trow * 4 + i;
        float ps = 0.f, pd = 0.f;
#pragma unroll
        for (int j = 0; j < 4; ++j) {
            ps = fmaf(acc[i][j], asr[j], ps);
            pd = fmaf(acc[i][j], adr[j], pd);
        }
        // reduce across the 16 threads (tcol group) owning this row
#pragma unroll
        for (int off = 8; off >= 1; off >>= 1) {
            ps += __shfl_xor(ps, off);
            pd += __shfl_xor(pd, off);
        }
        if (row < N_NODES) {
            float4 o = make_float4(acc[i][0], acc[i][1], acc[i][2], acc[i][3]);
            *(float4*)&hW[row * 64 + tcol * 4] = o;
            if (tcol == 0) { s_src[row] = ps; s_dst[row] = pd; }
        }
    }
}

// ---------------- attention softmax + aggregation (one wave per dst node) ----------------

__global__ __launch_bounds__(256) void k_agg(
    const float* __restrict__ hW, const int* __restrict__ col,
    const int* __restrict__ rowptr, const float* __restrict__ s_src,
    const float* __restrict__ s_dst, const float* __restrict__ bias,
    float* __restrict__ hout, int do_relu)
{
    int wave = threadIdx.x >> 6;
    int lane = threadIdx.x & 63;
    int node = blockIdx.x * 4 + wave;
    if (node >= N_NODES) return;

    int row = rowptr[node];
    int end = rowptr[node + 1];
    int deg = end - row;
    float sdi = s_dst[node];
    float acc = 0.f;

    if (deg <= 64) {
        int c = 0;
        float e = -FLT_MAX;
        if (lane < deg) {
            c = col[row + lane];
            float ee = s_src[c] + sdi;
            e = (ee >= 0.f) ? ee : NEG_SLOPE * ee;
        }
        float m = e;
#pragma unroll
        for (int off = 32; off >= 1; off >>= 1) m = fmaxf(m, __shfl_xor(m, off));
        float p = (lane < deg) ? __expf(e - m) : 0.f;
        float denom = p;
#pragma unroll
        for (int off = 32; off >= 1; off >>= 1) denom += __shfl_xor(denom, off);
        float inv = 1.f / denom;

        for (int j = 0; j < deg; j += 4) {
            int cj[4]; float al[4]; float vals[4];
#pragma unroll
            for (int u = 0; u < 4; ++u) {
                int jj = j + u;
                int jv = (jj < deg) ? jj : 0;
                cj[u] = __shfl(c, jv);
                float pv = __shfl(p, jv);
                al[u] = (jj < deg) ? pv * inv : 0.f;
            }
#pragma unroll
            for (int u = 0; u < 4; ++u) vals[u] = hW[cj[u] * 64 + lane];
#pragma unroll
            for (int u = 0; u < 4; ++u) acc = fmaf(al[u], vals[u], acc);
        }
    } else {
        // generic path (deg > 64): statistically never hit, kept for correctness
        float m = -FLT_MAX;
        for (int j = row + lane; j < end; j += 64) {
            float ee = s_src[col[j]] + sdi;
            ee = (ee >= 0.f) ? ee : NEG_SLOPE * ee;
            m = fmaxf(m, ee);
        }
#pragma unroll
        for (int off = 32; off >= 1; off >>= 1) m = fmaxf(m, __shfl_xor(m, off));
        float denom = 0.f;
        for (int j = row + lane; j < end; j += 64) {
            float ee = s_src[col[j]] + sdi;
            ee = (ee >= 0.f) ? ee : NEG_SLOPE * ee;
            denom += __expf(ee - m);
        }
#pragma unroll
        for (int off = 32; off >= 1; off >>= 1) denom += __shfl_xor(denom, off);
        float inv = 1.f / denom;
        for (int j = row; j < end; ++j) {
            int cc = col[j];  // wave-uniform broadcast load
            float ee = s_src[cc] + sdi;
            ee = (ee >= 0.f) ? ee : NEG_SLOPE * ee;
            acc = fmaf(__expf(ee - m) * inv, hW[cc * 64 + lane], acc);
        }
    }

    float o = acc + bias[lane];
    if (do_relu) o = fmaxf(o, 0.f);
    hout[node * 64 + lane] = o;
}

// ---------------- mean pool + linear head ----------------

__device__ __forceinline__ int lower_bound_dev(const int* __restrict__ a, int n, int v) {
    int lo = 0, hi = n;
    while (lo < hi) {
        int mid = (lo + hi) >> 1;
        if (a[mid] < v) lo = mid + 1; else hi = mid;
    }
    return lo;
}

__global__ __launch_bounds__(256) void k_pool(
    const float* __restrict__ h, const int* __restrict__ batch,
    const float* __restrict__ W_out, const float* __restrict__ b_out,
    float* __restrict__ out)
{
    int g = blockIdx.x;
    int t = threadIdx.x, wave = t >> 6, lane = t & 63;
    int start = lower_bound_dev(batch, N_NODES, g);
    int end = lower_bound_dev(batch, N_NODES, g + 1);

    float acc = 0.f;
    for (int n = start + wave; n < end; n += 4) acc += h[n * 64 + lane];

    __shared__ float s[4][64];
    __shared__ float mean[64];
    s[wave][lane] = acc;
    __syncthreads();
    if (t < 64) {
        float tot = s[0][t] + s[1][t] + s[2][t] + s[3][t];
        int cnt = end - start;
        mean[t] = tot / fmaxf((float)cnt, 1.f);
    }
    __syncthreads();
    if (wave < 2) {
        float v = mean[lane] * W_out[lane * 2 + wave];
#pragma unroll
        for (int off = 32; off >= 1; off >>= 1) v += __shfl_xor(v, off);
        if (lane == 0) out[g * 2 + wave] = v + b_out[wave];
    }
}

// ---------------- launch ----------------

extern "C" void kernel_launch(void* const* d_in, const int* in_sizes, int n_in,
                              void* d_out, int out_size, void* d_ws, size_t ws_size,
                              hipStream_t stream) {
    const int*   x       = (const int*)d_in[0];
    const int*   edge    = (const int*)d_in[1];   // [2][E]
    const int*   batch   = (const int*)d_in[2];
    const float* embed   = (const float*)d_in[3]; // [2][64]
    const float* Ws      = (const float*)d_in[4]; // [3][64][64]
    const float* a_srcs  = (const float*)d_in[5]; // [3][64]
    const float* a_dsts  = (const float*)d_in[6];
    const float* biases  = (const float*)d_in[7];
    const float* W_out   = (const float*)d_in[8]; // [64][2]
    const float* b_out   = (const float*)d_in[9];
    float* out = (float*)d_out;

    char* ws = (char*)d_ws;
    size_t off = 0;
    auto alloc = [&](size_t bytes) -> void* {
        void* p = ws + off;
        off += (bytes + 255) & ~(size_t)255;
        return p;
    };
    float* hbuf0  = (float*)alloc((size_t)N_NODES * 64 * sizeof(float)); // layer io
    float* hbuf1  = (float*)alloc((size_t)N_NODES * 64 * sizeof(float)); // hW
    float* s_src  = (float*)alloc((size_t)N_NODES * sizeof(float));
    float* s_dst  = (float*)alloc((size_t)N_NODES * sizeof(float));
    int*   deg    = (int*)alloc((size_t)N_NODES * sizeof(int));
    int*   tmp    = (int*)alloc((size_t)N_NODES * sizeof(int));
    int*   bsum   = (int*)alloc((size_t)SCAN_BLOCKS * sizeof(int));
    int*   boffs  = (int*)alloc((size_t)SCAN_BLOCKS * sizeof(int));
    int*   rowptr = (int*)alloc((size_t)(N_NODES + 1) * sizeof(int));
    int*   nxt    = (int*)alloc((size_t)(N_NODES + 1) * sizeof(int));
    int*   colA   = (int*)alloc((size_t)ETOT * sizeof(int));

    const int* e0 = edge;
    const int* e1 = edge + N_EDGES;

    // CSR build (by dst, self loops included)
    k_init_deg<<<(N_NODES + 255) / 256, 256, 0, stream>>>(deg);
    k_hist<<<(N_EDGES + 255) / 256, 256, 0, stream>>>(e1, deg);
    k_scan1<<<SCAN_BLOCKS, SCAN_CHUNK, 0, stream>>>(deg, tmp, bsum);
    k_scan2<<<1, 256, 0, stream>>>(bsum, boffs);
    k_scan3<<<(N_NODES + 255) / 256, 256, 0, stream>>>(tmp, boffs, rowptr, nxt);
    k_scatter<<<(ETOT + 255) / 256, 256, 0, stream>>>(e0, e1, nxt, colA);

    const int gemm_blocks = (N_NODES + 63) / 64;  // 1563
    const float* hin = nullptr;
    for (int l = 0; l < 3; ++l) {
        k_gemm_score<<<gemm_blocks, 256, 0, stream>>>(
            hin, x, embed, Ws + (size_t)l * 4096, a_srcs + l * 64, a_dsts + l * 64,
            hbuf1, s_src, s_dst, (l == 0) ? 1 : 0);
        k_agg<<<(N_NODES + 3) / 4, 256, 0, stream>>>(
            hbuf1, colA, rowptr, s_src, s_dst, biases + l * 64, hbuf0, (l < 2) ? 1 : 0);
        hin = hbuf0;
    }
    k_pool<<<N_GRAPHS, 256, 0, stream>>>(hbuf0, batch, W_out, b_out, out);
}

// Round 2
// 486.938 us; speedup vs baseline: 1.2798x; 1.2798x over previous
//
#include <hip/hip_runtime.h>
#include <hip/hip_bf16.h>
#include <float.h>

#define N_NODES 100000
#define N_EDGES 1600000
#define HIDDEN 64
#define N_GRAPHS 128
#define NEG_SLOPE 0.2f
#define ETOT (N_EDGES + N_NODES)

#define BSHIFT 10
#define NB ((N_NODES + 1023) >> BSHIFT)   // 98 buckets of 1024 nodes
#define PAIR_CHUNK 8192
#define PAIR_BLOCKS ((N_EDGES + PAIR_CHUNK - 1) / PAIR_CHUNK)  // 196

// ---------------- bucketed CSR build ----------------

__global__ void k_zero_cnt(int* __restrict__ cnt) {
    int t = threadIdx.x;
    if (t < NB) cnt[t] = 0;
}

__global__ __launch_bounds__(256) void k_bucket_hist(const int* __restrict__ dst,
                                                     int* __restrict__ bucket_cnt) {
    __shared__ int h[NB];
    int t = threadIdx.x;
    if (t < NB) h[t] = 0;
    __syncthreads();
    int stride = gridDim.x * blockDim.x;
    for (int e = blockIdx.x * blockDim.x + t; e < N_EDGES; e += stride)
        atomicAdd(&h[dst[e] >> BSHIFT], 1);
    __syncthreads();
    if (t < NB) atomicAdd(&bucket_cnt[t], h[t]);
}

__global__ void k_bucket_scan(const int* __restrict__ bucket_cnt,
                              int* __restrict__ pair_start,
                              int* __restrict__ bucket_next) {
    __shared__ int s[128];
    int t = threadIdx.x;
    int v = (t < NB) ? bucket_cnt[t] : 0;
    s[t] = v;
    __syncthreads();
    for (int off = 1; off < 128; off <<= 1) {
        int u = (t >= off) ? s[t - off] : 0;
        __syncthreads();
        s[t] += u;
        __syncthreads();
    }
    if (t < NB) {
        int ex = s[t] - v;
        pair_start[t] = ex;
        bucket_next[t] = ex;
    }
    if (t == 0) pair_start[NB] = N_EDGES;
}

__global__ __launch_bounds__(256) void k_pair_scatter(
    const int* __restrict__ e0, const int* __restrict__ e1,
    int* __restrict__ bucket_next, int2* __restrict__ pairs)
{
    __shared__ int cnt[NB];
    __shared__ int base[NB];
    int t = threadIdx.x;
    int ebase = blockIdx.x * PAIR_CHUNK;
    int ecount = min(PAIR_CHUNK, N_EDGES - ebase);

    if (t < NB) cnt[t] = 0;
    __syncthreads();
    for (int i = t; i < ecount; i += 256)
        atomicAdd(&cnt[e1[ebase + i] >> BSHIFT], 1);
    __syncthreads();
    if (t < NB) {
        base[t] = atomicAdd(&bucket_next[t], cnt[t]);
        cnt[t] = 0;
    }
    __syncthreads();
    for (int i = t; i < ecount; i += 256) {
        int s = e0[ebase + i];
        int d = e1[ebase + i];
        int b = d >> BSHIFT;
        int idx = atomicAdd(&cnt[b], 1);
        pairs[base[b] + idx] = make_int2(s, d);
    }
}

// One block per bucket: local degree histogram + scan + col scatter, all in LDS.
// Self loop occupies slot 0 of each row.
__global__ __launch_bounds__(1024) void k_csr_bucket(
    const int2* __restrict__ pairs, const int* __restrict__ pair_start,
    int* __restrict__ rowptr, int* __restrict__ col)
{
    __shared__ int deg[1024];
    __shared__ int excl[1024];
    __shared__ int s[1024];
    int b = blockIdx.x;
    int t = threadIdx.x;
    int nb = b << BSHIFT;
    int nodes = min(1024, N_NODES - nb);

    deg[t] = (t < nodes) ? 1 : 0;   // self loop
    __syncthreads();
    int p0 = pair_start[b], p1 = pair_start[b + 1];
    for (int i = p0 + t; i < p1; i += 1024)
        atomicAdd(&deg[pairs[i].y - nb], 1);
    __syncthreads();

    int val = deg[t];
    s[t] = val;
    __syncthreads();
    for (int off = 1; off < 1024; off <<= 1) {
        int u = (t >= off) ? s[t - off] : 0;
        __syncthreads();
        s[t] += u;
        __syncthreads();
    }
    int ex = s[t] - val;  // exclusive prefix of local degrees
    excl[t] = ex;

    int colbase = p0 + nb;  // nb == #self-loops in preceding buckets
    if (t < nodes) {
        rowptr[nb + t] = colbase + ex;
        col[colbase + ex] = nb + t;  // self loop at slot 0
    }
    if (b == NB - 1 && t == 0) rowptr[N_NODES] = ETOT;

    deg[t] = 1;  // slot 0 taken by self loop
    __syncthreads();
    for (int i = p0 + t; i < p1; i += 1024) {
        int2 pr = pairs[i];
        int li = pr.y - nb;
        int pos = colbase + excl[li] + atomicAdd(&deg[li], 1);
        col[pos] = pr.x;
    }
}

// ---------------- per-layer GEMM + attention scores ----------------

__global__ __launch_bounds__(256) void k_gemm_score(
    const float* __restrict__ h, const int* __restrict__ x,
    const float* __restrict__ embed, const float* __restrict__ W,
    const float* __restrict__ a_s, const float* __restrict__ a_d,
    float* __restrict__ hW, float* __restrict__ s_src, float* __restrict__ s_dst,
    int layer0)
{
    __shared__ float Wl[64 * 64];
    __shared__ float hT[64 * 68];  // [k][r], pitch 68
    int t = threadIdx.x;
    int r0 = blockIdx.x * 64;

    for (int i = t; i < 4096; i += 256) Wl[i] = W[i];
    for (int i = t; i < 4096; i += 256) {
        int r = i >> 6, k = i & 63;
        int row = r0 + r;
        float v = 0.f;
        if (row < N_NODES)
            v = layer0 ? embed[x[row] * 64 + k] : h[row * 64 + k];
        hT[k * 68 + r] = v;
    }
    __syncthreads();

    int tcol = t & 15;
    int trow = t >> 4;
    float acc[4][4];
#pragma unroll
    for (int i = 0; i < 4; ++i)
#pragma unroll
        for (int j = 0; j < 4; ++j) acc[i][j] = 0.f;

    for (int k = 0; k < 64; ++k) {
        float4 va = *(const float4*)&hT[k * 68 + trow * 4];
        float4 vb = *(const float4*)&Wl[k * 64 + tcol * 4];
        float a[4] = {va.x, va.y, va.z, va.w};
        float bb[4] = {vb.x, vb.y, vb.z, vb.w};
#pragma unroll
        for (int i = 0; i < 4; ++i)
#pragma unroll
            for (int j = 0; j < 4; ++j) acc[i][j] = fmaf(a[i], bb[j], acc[i][j]);
    }

    float4 as4 = *(const float4*)&a_s[tcol * 4];
    float4 ad4 = *(const float4*)&a_d[tcol * 4];
    float asr[4] = {as4.x, as4.y, as4.z, as4.w};
    float adr[4] = {ad4.x, ad4.y, ad4.z, ad4.w};

#pragma unroll
    for (int i = 0; i < 4; ++i) {
        int row = r0 + trow * 4 + i;
        float ps = 0.f, pd = 0.f;
#pragma unroll
        for (int j = 0; j < 4; ++j) {
            ps = fmaf(acc[i][j], asr[j], ps);
            pd = fmaf(acc[i][j], adr[j], pd);
        }
#pragma unroll
        for (int off = 8; off >= 1; off >>= 1) {
            ps += __shfl_xor(ps, off);
            pd += __shfl_xor(pd, off);
        }
        if (row < N_NODES) {
            float4 o = make_float4(acc[i][0], acc[i][1], acc[i][2], acc[i][3]);
            *(float4*)&hW[row * 64 + tcol * 4] = o;
            if (tcol == 0) { s_src[row] = ps; s_dst[row] = pd; }
        }
    }
}

// ---------------- attention softmax + aggregation (one wave per dst node) ----------------

__global__ __launch_bounds__(256) void k_agg(
    const float* __restrict__ hW, const int* __restrict__ col,
    const int* __restrict__ rowptr, const float* __restrict__ s_src,
    const float* __restrict__ s_dst, const float* __restrict__ bias,
    float* __restrict__ hout, int do_relu)
{
    int wave = threadIdx.x >> 6;
    int lane = threadIdx.x & 63;
    int node = blockIdx.x * 4 + wave;
    if (node >= N_NODES) return;

    int row = rowptr[node];
    int end = rowptr[node + 1];
    int deg = end - row;
    float sdi = s_dst[node];
    float acc = 0.f;

    if (deg <= 64) {
        int c = 0;
        float e = -FLT_MAX;
        if (lane < deg) {
            c = col[row + lane];
            float ee = s_src[c] + sdi;
            e = (ee >= 0.f) ? ee : NEG_SLOPE * ee;
        }
        float m = e;
#pragma unroll
        for (int off = 32; off >= 1; off >>= 1) m = fmaxf(m, __shfl_xor(m, off));
        float p = (lane < deg) ? __expf(e - m) : 0.f;
        float denom = p;
#pragma unroll
        for (int off = 32; off >= 1; off >>= 1) denom += __shfl_xor(denom, off);
        float inv = 1.f / denom;

        for (int j = 0; j < deg; j += 4) {
            int cj[4]; float al[4]; float vals[4];
#pragma unroll
            for (int u = 0; u < 4; ++u) {
                int jj = j + u;
                int jv = (jj < deg) ? jj : 0;
                cj[u] = __shfl(c, jv);
                float pv = __shfl(p, jv);
                al[u] = (jj < deg) ? pv * inv : 0.f;
            }
#pragma unroll
            for (int u = 0; u < 4; ++u) vals[u] = hW[cj[u] * 64 + lane];
#pragma unroll
            for (int u = 0; u < 4; ++u) acc = fmaf(al[u], vals[u], acc);
        }
    } else {
        float m = -FLT_MAX;
        for (int j = row + lane; j < end; j += 64) {
            float ee = s_src[col[j]] + sdi;
            ee = (ee >= 0.f) ? ee : NEG_SLOPE * ee;
            m = fmaxf(m, ee);
        }
#pragma unroll
        for (int off = 32; off >= 1; off >>= 1) m = fmaxf(m, __shfl_xor(m, off));
        float denom = 0.f;
        for (int j = row + lane; j < end; j += 64) {
            float ee = s_src[col[j]] + sdi;
            ee = (ee >= 0.f) ? ee : NEG_SLOPE * ee;
            denom += __expf(ee - m);
        }
#pragma unroll
        for (int off = 32; off >= 1; off >>= 1) denom += __shfl_xor(denom, off);
        float inv = 1.f / denom;
        for (int j = row; j < end; ++j) {
            int cc = col[j];
            float ee = s_src[cc] + sdi;
            ee = (ee >= 0.f) ? ee : NEG_SLOPE * ee;
            acc = fmaf(__expf(ee - m) * inv, hW[cc * 64 + lane], acc);
        }
    }

    float o = acc + bias[lane];
    if (do_relu) o = fmaxf(o, 0.f);
    hout[node * 64 + lane] = o;
}

// ---------------- mean pool + linear head ----------------

__device__ __forceinline__ int lower_bound_dev(const int* __restrict__ a, int n, int v) {
    int lo = 0, hi = n;
    while (lo < hi) {
        int mid = (lo + hi) >> 1;
        if (a[mid] < v) lo = mid + 1; else hi = mid;
    }
    return lo;
}

__global__ __launch_bounds__(256) void k_pool(
    const float* __restrict__ h, const int* __restrict__ batch,
    const float* __restrict__ W_out, const float* __restrict__ b_out,
    float* __restrict__ out)
{
    int g = blockIdx.x;
    int t = threadIdx.x, wave = t >> 6, lane = t & 63;
    int start = lower_bound_dev(batch, N_NODES, g);
    int end = lower_bound_dev(batch, N_NODES, g + 1);

    float acc = 0.f;
    for (int n = start + wave; n < end; n += 4) acc += h[n * 64 + lane];

    __shared__ float s[4][64];
    __shared__ float mean[64];
    s[wave][lane] = acc;
    __syncthreads();
    if (t < 64) {
        float tot = s[0][t] + s[1][t] + s[2][t] + s[3][t];
        int cnt = end - start;
        mean[t] = tot / fmaxf((float)cnt, 1.f);
    }
    __syncthreads();
    if (wave < 2) {
        float v = mean[lane] * W_out[lane * 2 + wave];
#pragma unroll
        for (int off = 32; off >= 1; off >>= 1) v += __shfl_xor(v, off);
        if (lane == 0) out[g * 2 + wave] = v + b_out[wave];
    }
}

// ---------------- launch ----------------

extern "C" void kernel_launch(void* const* d_in, const int* in_sizes, int n_in,
                              void* d_out, int out_size, void* d_ws, size_t ws_size,
                              hipStream_t stream) {
    const int*   x       = (const int*)d_in[0];
    const int*   edge    = (const int*)d_in[1];   // [2][E]
    const int*   batch   = (const int*)d_in[2];
    const float* embed   = (const float*)d_in[3];
    const float* Ws      = (const float*)d_in[4];
    const float* a_srcs  = (const float*)d_in[5];
    const float* a_dsts  = (const float*)d_in[6];
    const float* biases  = (const float*)d_in[7];
    const float* W_out   = (const float*)d_in[8];
    const float* b_out   = (const float*)d_in[9];
    float* out = (float*)d_out;

    char* ws = (char*)d_ws;
    size_t off = 0;
    auto alloc = [&](size_t bytes) -> void* {
        void* p = ws + off;
        off += (bytes + 255) & ~(size_t)255;
        return p;
    };
    float* hbuf0   = (float*)alloc((size_t)N_NODES * 64 * sizeof(float)); // layer io
    float* hbuf1   = (float*)alloc((size_t)N_NODES * 64 * sizeof(float)); // hW
    float* s_src   = (float*)alloc((size_t)N_NODES * sizeof(float));
    float* s_dst   = (float*)alloc((size_t)N_NODES * sizeof(float));
    int*   rowptr  = (int*)alloc((size_t)(N_NODES + 1) * sizeof(int));
    int*   colA    = (int*)alloc((size_t)ETOT * sizeof(int));
    int*   bcnt    = (int*)alloc((size_t)NB * sizeof(int));
    int*   pstart  = (int*)alloc((size_t)(NB + 1) * sizeof(int));
    int*   bnext   = (int*)alloc((size_t)NB * sizeof(int));
    // pairs alias hbuf1 (12.8 MB <= 25.6 MB; dead before first GEMM writes hbuf1)
    int2*  pairs   = (int2*)hbuf1;

    const int* e0 = edge;
    const int* e1 = edge + N_EDGES;

    // bucketed CSR build (by dst, self loops at slot 0 of each row)
    k_zero_cnt<<<1, 128, 0, stream>>>(bcnt);
    k_bucket_hist<<<512, 256, 0, stream>>>(e1, bcnt);
    k_bucket_scan<<<1, 128, 0, stream>>>(bcnt, pstart, bnext);
    k_pair_scatter<<<PAIR_BLOCKS, 256, 0, stream>>>(e0, e1, bnext, pairs);
    k_csr_bucket<<<NB, 1024, 0, stream>>>(pairs, pstart, rowptr, colA);

    const int gemm_blocks = (N_NODES + 63) / 64;
    const float* hin = nullptr;
    for (int l = 0; l < 3; ++l) {
        k_gemm_score<<<gemm_blocks, 256, 0, stream>>>(
            hin, x, embed, Ws + (size_t)l * 4096, a_srcs + l * 64, a_dsts + l * 64,
            hbuf1, s_src, s_dst, (l == 0) ? 1 : 0);
        k_agg<<<(N_NODES + 3) / 4, 256, 0, stream>>>(
            hbuf1, colA, rowptr, s_src, s_dst, biases + l * 64, hbuf0, (l < 2) ? 1 : 0);
        hin = hbuf0;
    }
    k_pool<<<N_GRAPHS, 256, 0, stream>>>(hbuf0, batch, W_out, b_out, out);
}

// Round 3
// 416.204 us; speedup vs baseline: 1.4973x; 1.1699x over previous
//
#include <hip/hip_runtime.h>
#include <hip/hip_bf16.h>
#include <float.h>

#define N_NODES 100000
#define N_EDGES 1600000
#define HIDDEN 64
#define N_GRAPHS 128
#define NEG_SLOPE 0.2f
#define ETOT (N_EDGES + N_NODES)

#define BSHIFT 10
#define NB ((N_NODES + 1023) >> BSHIFT)   // 98 buckets of 1024 nodes
#define PAIR_CHUNK 8192
#define PAIR_BLOCKS ((N_EDGES + PAIR_CHUNK - 1) / PAIR_CHUNK)  // 196

__device__ __forceinline__ unsigned short f2bf(float f) {
    unsigned u = __float_as_uint(f);
    unsigned r = (u + 0x7FFFu + ((u >> 16) & 1u)) >> 16;  // RNE
    return (unsigned short)r;
}

// ---------------- bucketed CSR build ----------------

__global__ void k_zero_cnt(int* __restrict__ cnt) {
    int t = threadIdx.x;
    if (t < NB) cnt[t] = 0;
}

__global__ __launch_bounds__(256) void k_bucket_hist(const int* __restrict__ dst,
                                                     int* __restrict__ bucket_cnt) {
    __shared__ int h[NB];
    int t = threadIdx.x;
    if (t < NB) h[t] = 0;
    __syncthreads();
    int stride = gridDim.x * blockDim.x;
    for (int e = blockIdx.x * blockDim.x + t; e < N_EDGES; e += stride)
        atomicAdd(&h[dst[e] >> BSHIFT], 1);
    __syncthreads();
    if (t < NB) atomicAdd(&bucket_cnt[t], h[t]);
}

__global__ void k_bucket_scan(const int* __restrict__ bucket_cnt,
                              int* __restrict__ pair_start,
                              int* __restrict__ bucket_next) {
    __shared__ int s[128];
    int t = threadIdx.x;
    int v = (t < NB) ? bucket_cnt[t] : 0;
    s[t] = v;
    __syncthreads();
    for (int off = 1; off < 128; off <<= 1) {
        int u = (t >= off) ? s[t - off] : 0;
        __syncthreads();
        s[t] += u;
        __syncthreads();
    }
    if (t < NB) {
        int ex = s[t] - v;
        pair_start[t] = ex;
        bucket_next[t] = ex;
    }
    if (t == 0) pair_start[NB] = N_EDGES;
}

__global__ __launch_bounds__(256) void k_pair_scatter(
    const int* __restrict__ e0, const int* __restrict__ e1,
    int* __restrict__ bucket_next, int2* __restrict__ pairs)
{
    __shared__ int cnt[NB];
    __shared__ int base[NB];
    int t = threadIdx.x;
    int ebase = blockIdx.x * PAIR_CHUNK;
    int ecount = min(PAIR_CHUNK, N_EDGES - ebase);

    if (t < NB) cnt[t] = 0;
    __syncthreads();
    for (int i = t; i < ecount; i += 256)
        atomicAdd(&cnt[e1[ebase + i] >> BSHIFT], 1);
    __syncthreads();
    if (t < NB) {
        base[t] = atomicAdd(&bucket_next[t], cnt[t]);
        cnt[t] = 0;
    }
    __syncthreads();
    for (int i = t; i < ecount; i += 256) {
        int s = e0[ebase + i];
        int d = e1[ebase + i];
        int b = d >> BSHIFT;
        int idx = atomicAdd(&cnt[b], 1);
        pairs[base[b] + idx] = make_int2(s, d);
    }
}

// One block per bucket: local degree histogram + wave-scan + col scatter in LDS.
// Self loop occupies slot 0 of each row.
__global__ __launch_bounds__(1024) void k_csr_bucket(
    const int2* __restrict__ pairs, const int* __restrict__ pair_start,
    int* __restrict__ rowptr, int* __restrict__ col)
{
    __shared__ int deg[1024];
    __shared__ int excl[1024];
    __shared__ int wsum[16];
    int b = blockIdx.x;
    int t = threadIdx.x;
    int nb = b << BSHIFT;
    int nodes = min(1024, N_NODES - nb);

    deg[t] = (t < nodes) ? 1 : 0;   // self loop
    __syncthreads();
    int p0 = pair_start[b], p1 = pair_start[b + 1];
    for (int i = p0 + t; i < p1; i += 1024)
        atomicAdd(&deg[pairs[i].y - nb], 1);
    __syncthreads();

    int val = deg[t];
    int x = val;
#pragma unroll
    for (int off = 1; off < 64; off <<= 1) {
        int y = __shfl_up(x, off);
        if ((t & 63) >= off) x += y;
    }
    if ((t & 63) == 63) wsum[t >> 6] = x;
    __syncthreads();
    if (t == 0) {
        int s = 0;
#pragma unroll
        for (int i = 0; i < 16; ++i) { int v = wsum[i]; wsum[i] = s; s += v; }
    }
    __syncthreads();
    int ex = x - val + wsum[t >> 6];  // exclusive prefix of local degrees
    excl[t] = ex;

    int colbase = p0 + nb;  // nb == #self-loops in preceding buckets
    if (t < nodes) {
        rowptr[nb + t] = colbase + ex;
        col[colbase + ex] = nb + t;  // self loop at slot 0
    }
    if (b == NB - 1 && t == 0) rowptr[N_NODES] = ETOT;

    deg[t] = 1;  // slot 0 taken by self loop
    __syncthreads();
    for (int i = p0 + t; i < p1; i += 1024) {
        int2 pr = pairs[i];
        int li = pr.y - nb;
        int pos = colbase + excl[li] + atomicAdd(&deg[li], 1);
        col[pos] = pr.x;
    }
}

// ---------------- per-layer GEMM + attention scores ----------------
// hWb (bf16) = h @ W ; s_src = hW @ a_s ; s_dst = hW @ a_d  (scores fp32)

__global__ __launch_bounds__(256) void k_gemm_score(
    const float* __restrict__ h, const int* __restrict__ x,
    const float* __restrict__ embed, const float* __restrict__ W,
    const float* __restrict__ a_s, const float* __restrict__ a_d,
    unsigned short* __restrict__ hWb, float* __restrict__ s_src,
    float* __restrict__ s_dst, int layer0)
{
    __shared__ float Wl[64 * 64];
    __shared__ float hT[64 * 68];  // [k][r], pitch 68
    int t = threadIdx.x;
    int r0 = blockIdx.x * 64;

    for (int i = t; i < 4096; i += 256) Wl[i] = W[i];
    for (int i = t; i < 4096; i += 256) {
        int r = i >> 6, k = i & 63;
        int row = r0 + r;
        float v = 0.f;
        if (row < N_NODES)
            v = layer0 ? embed[x[row] * 64 + k] : h[row * 64 + k];
        hT[k * 68 + r] = v;
    }
    __syncthreads();

    int tcol = t & 15;
    int trow = t >> 4;
    float acc[4][4];
#pragma unroll
    for (int i = 0; i < 4; ++i)
#pragma unroll
        for (int j = 0; j < 4; ++j) acc[i][j] = 0.f;

    for (int k = 0; k < 64; ++k) {
        float4 va = *(const float4*)&hT[k * 68 + trow * 4];
        float4 vb = *(const float4*)&Wl[k * 64 + tcol * 4];
        float a[4] = {va.x, va.y, va.z, va.w};
        float bb[4] = {vb.x, vb.y, vb.z, vb.w};
#pragma unroll
        for (int i = 0; i < 4; ++i)
#pragma unroll
            for (int j = 0; j < 4; ++j) acc[i][j] = fmaf(a[i], bb[j], acc[i][j]);
    }

    float4 as4 = *(const float4*)&a_s[tcol * 4];
    float4 ad4 = *(const float4*)&a_d[tcol * 4];
    float asr[4] = {as4.x, as4.y, as4.z, as4.w};
    float adr[4] = {ad4.x, ad4.y, ad4.z, ad4.w};

#pragma unroll
    for (int i = 0; i < 4; ++i) {
        int row = r0 + trow * 4 + i;
        float ps = 0.f, pd = 0.f;
#pragma unroll
        for (int j = 0; j < 4; ++j) {
            ps = fmaf(acc[i][j], asr[j], ps);
            pd = fmaf(acc[i][j], adr[j], pd);
        }
#pragma unroll
        for (int off = 8; off >= 1; off >>= 1) {
            ps += __shfl_xor(ps, off);
            pd += __shfl_xor(pd, off);
        }
        if (row < N_NODES) {
            ushort4 o;
            o.x = f2bf(acc[i][0]); o.y = f2bf(acc[i][1]);
            o.z = f2bf(acc[i][2]); o.w = f2bf(acc[i][3]);
            *(ushort4*)&hWb[row * 64 + tcol * 4] = o;
            if (tcol == 0) { s_src[row] = ps; s_dst[row] = pd; }
        }
    }
}

// ---------------- attention softmax + aggregation (one wave per dst node) ----------------
// hWb gathered as bf16; alpha/col stashed in LDS; 2 edges per iter (half-wave each).

__global__ __launch_bounds__(256) void k_agg(
    const unsigned short* __restrict__ hWb, const int* __restrict__ col,
    const int* __restrict__ rowptr, const float* __restrict__ s_src,
    const float* __restrict__ s_dst, const float* __restrict__ bias,
    float* __restrict__ hout, int do_relu)
{
    __shared__ float2 stash[4][64];  // (alpha, elem-offset bits)
    int wave = threadIdx.x >> 6;
    int lane = threadIdx.x & 63;
    int node = blockIdx.x * 4 + wave;
    if (node >= N_NODES) return;

    int row = rowptr[node];
    int end = rowptr[node + 1];
    int deg = end - row;
    float sdi = s_dst[node];

    if (deg <= 64) {
        int c = 0;
        float e = -FLT_MAX;
        if (lane < deg) {
            c = col[row + lane];
            float ee = s_src[c] + sdi;
            e = (ee >= 0.f) ? ee : NEG_SLOPE * ee;
        }
        float m = e;
#pragma unroll
        for (int off = 32; off >= 1; off >>= 1) m = fmaxf(m, __shfl_xor(m, off));
        float p = (lane < deg) ? __expf(e - m) : 0.f;
        float denom = p;
#pragma unroll
        for (int off = 32; off >= 1; off >>= 1) denom += __shfl_xor(denom, off);
        float inv = 1.f / denom;
        // lanes >= deg stash alpha=0, offset=0 (harmless reads of hWb[0..])
        stash[wave][lane] = make_float2(p * inv, __int_as_float(c * 64));

        int half = lane >> 5;   // which edge of the pair
        int hl = lane & 31;     // feature pair index: features 2*hl, 2*hl+1
        float acc0 = 0.f, acc1 = 0.f;
        int degr = (deg + 7) & ~7;
        for (int j = half; j < degr; j += 8) {
            float2 ac0 = stash[wave][j];
            float2 ac2 = stash[wave][j + 2];
            float2 ac4 = stash[wave][j + 4];
            float2 ac6 = stash[wave][j + 6];
            unsigned v0 = *(const unsigned*)&hWb[__float_as_int(ac0.y) + hl * 2];
            unsigned v2 = *(const unsigned*)&hWb[__float_as_int(ac2.y) + hl * 2];
            unsigned v4 = *(const unsigned*)&hWb[__float_as_int(ac4.y) + hl * 2];
            unsigned v6 = *(const unsigned*)&hWb[__float_as_int(ac6.y) + hl * 2];
            acc0 = fmaf(ac0.x, __uint_as_float(v0 << 16), acc0);
            acc1 = fmaf(ac0.x, __uint_as_float(v0 & 0xFFFF0000u), acc1);
            acc0 = fmaf(ac2.x, __uint_as_float(v2 << 16), acc0);
            acc1 = fmaf(ac2.x, __uint_as_float(v2 & 0xFFFF0000u), acc1);
            acc0 = fmaf(ac4.x, __uint_as_float(v4 << 16), acc0);
            acc1 = fmaf(ac4.x, __uint_as_float(v4 & 0xFFFF0000u), acc1);
            acc0 = fmaf(ac6.x, __uint_as_float(v6 << 16), acc0);
            acc1 = fmaf(ac6.x, __uint_as_float(v6 & 0xFFFF0000u), acc1);
        }
        acc0 += __shfl_xor(acc0, 32);
        acc1 += __shfl_xor(acc1, 32);
        if (half == 0) {
            float2 bb = ((const float2*)bias)[hl];
            float o0 = acc0 + bb.x, o1 = acc1 + bb.y;
            if (do_relu) { o0 = fmaxf(o0, 0.f); o1 = fmaxf(o1, 0.f); }
            *(float2*)&hout[node * 64 + hl * 2] = make_float2(o0, o1);
        }
    } else {
        // generic path (deg > 64): statistically never hit
        float m = -FLT_MAX;
        for (int j = row + lane; j < end; j += 64) {
            float ee = s_src[col[j]] + sdi;
            ee = (ee >= 0.f) ? ee : NEG_SLOPE * ee;
            m = fmaxf(m, ee);
        }
#pragma unroll
        for (int off = 32; off >= 1; off >>= 1) m = fmaxf(m, __shfl_xor(m, off));
        float denom = 0.f;
        for (int j = row + lane; j < end; j += 64) {
            float ee = s_src[col[j]] + sdi;
            ee = (ee >= 0.f) ? ee : NEG_SLOPE * ee;
            denom += __expf(ee - m);
        }
#pragma unroll
        for (int off = 32; off >= 1; off >>= 1) denom += __shfl_xor(denom, off);
        float inv = 1.f / denom;
        float acc = 0.f;
        for (int j = row; j < end; ++j) {
            int cc = col[j];
            float ee = s_src[cc] + sdi;
            ee = (ee >= 0.f) ? ee : NEG_SLOPE * ee;
            unsigned hv = hWb[cc * 64 + lane];
            acc = fmaf(__expf(ee - m) * inv, __uint_as_float(hv << 16), acc);
        }
        float o = acc + bias[lane];
        if (do_relu) o = fmaxf(o, 0.f);
        hout[node * 64 + lane] = o;
    }
}

// ---------------- mean pool + linear head ----------------

__device__ __forceinline__ int lower_bound_dev(const int* __restrict__ a, int n, int v) {
    int lo = 0, hi = n;
    while (lo < hi) {
        int mid = (lo + hi) >> 1;
        if (a[mid] < v) lo = mid + 1; else hi = mid;
    }
    return lo;
}

__global__ __launch_bounds__(256) void k_pool(
    const float* __restrict__ h, const int* __restrict__ batch,
    const float* __restrict__ W_out, const float* __restrict__ b_out,
    float* __restrict__ out)
{
    int g = blockIdx.x;
    int t = threadIdx.x, wave = t >> 6, lane = t & 63;
    int start = lower_bound_dev(batch, N_NODES, g);
    int end = lower_bound_dev(batch, N_NODES, g + 1);

    float acc = 0.f;
    for (int n = start + wave; n < end; n += 4) acc += h[n * 64 + lane];

    __shared__ float s[4][64];
    __shared__ float mean[64];
    s[wave][lane] = acc;
    __syncthreads();
    if (t < 64) {
        float tot = s[0][t] + s[1][t] + s[2][t] + s[3][t];
        int cnt = end - start;
        mean[t] = tot / fmaxf((float)cnt, 1.f);
    }
    __syncthreads();
    if (wave < 2) {
        float v = mean[lane] * W_out[lane * 2 + wave];
#pragma unroll
        for (int off = 32; off >= 1; off >>= 1) v += __shfl_xor(v, off);
        if (lane == 0) out[g * 2 + wave] = v + b_out[wave];
    }
}

// ---------------- launch ----------------

extern "C" void kernel_launch(void* const* d_in, const int* in_sizes, int n_in,
                              void* d_out, int out_size, void* d_ws, size_t ws_size,
                              hipStream_t stream) {
    const int*   x       = (const int*)d_in[0];
    const int*   edge    = (const int*)d_in[1];   // [2][E]
    const int*   batch   = (const int*)d_in[2];
    const float* embed   = (const float*)d_in[3];
    const float* Ws      = (const float*)d_in[4];
    const float* a_srcs  = (const float*)d_in[5];
    const float* a_dsts  = (const float*)d_in[6];
    const float* biases  = (const float*)d_in[7];
    const float* W_out   = (const float*)d_in[8];
    const float* b_out   = (const float*)d_in[9];
    float* out = (float*)d_out;

    char* ws = (char*)d_ws;
    size_t off = 0;
    auto alloc = [&](size_t bytes) -> void* {
        void* p = ws + off;
        off += (bytes + 255) & ~(size_t)255;
        return p;
    };
    float*          hbuf0  = (float*)alloc((size_t)N_NODES * 64 * sizeof(float));  // layer io fp32
    unsigned short* hWb    = (unsigned short*)alloc((size_t)N_NODES * 64 * sizeof(unsigned short));
    float* s_src   = (float*)alloc((size_t)N_NODES * sizeof(float));
    float* s_dst   = (float*)alloc((size_t)N_NODES * sizeof(float));
    int*   rowptr  = (int*)alloc((size_t)(N_NODES + 1) * sizeof(int));
    int*   colA    = (int*)alloc((size_t)ETOT * sizeof(int));
    int*   bcnt    = (int*)alloc((size_t)NB * sizeof(int));
    int*   pstart  = (int*)alloc((size_t)(NB + 1) * sizeof(int));
    int*   bnext   = (int*)alloc((size_t)NB * sizeof(int));
    int2*  pairs   = (int2*)alloc((size_t)N_EDGES * sizeof(int2));  // dead after CSR build

    const int* e0 = edge;
    const int* e1 = edge + N_EDGES;

    // bucketed CSR build (by dst, self loops at slot 0 of each row)
    k_zero_cnt<<<1, 128, 0, stream>>>(bcnt);
    k_bucket_hist<<<512, 256, 0, stream>>>(e1, bcnt);
    k_bucket_scan<<<1, 128, 0, stream>>>(bcnt, pstart, bnext);
    k_pair_scatter<<<PAIR_BLOCKS, 256, 0, stream>>>(e0, e1, bnext, pairs);
    k_csr_bucket<<<NB, 1024, 0, stream>>>(pairs, pstart, rowptr, colA);

    const int gemm_blocks = (N_NODES + 63) / 64;
    const float* hin = nullptr;
    for (int l = 0; l < 3; ++l) {
        k_gemm_score<<<gemm_blocks, 256, 0, stream>>>(
            hin, x, embed, Ws + (size_t)l * 4096, a_srcs + l * 64, a_dsts + l * 64,
            hWb, s_src, s_dst, (l == 0) ? 1 : 0);
        k_agg<<<(N_NODES + 3) / 4, 256, 0, stream>>>(
            hWb, colA, rowptr, s_src, s_dst, biases + l * 64, hbuf0, (l < 2) ? 1 : 0);
        hin = hbuf0;
    }
    k_pool<<<N_GRAPHS, 256, 0, stream>>>(hbuf0, batch, W_out, b_out, out);
}